// Round 8
// baseline (34.757 us; speedup 1.0000x reference)
//
#include <hip/hip_runtime.h>

// out[b,o,ds] = sum_i x[b,i] * peso[o,i,ds] for i where mask[o,i]==1
// B=256, IN=1024, OUT=512, DS=128, ~10% (o,i) kept; mask values exactly {0,1}.
//
// MFMA v2: per o, out_o[256,128] = x[:,S_o] @ W_o[S_o,:], compacted K.
// 2 blocks/o (128 b-rows), 512 thr / 8 waves. ALL K (<=128, zero-padded)
// staged in one pass -> ONE barrier common-case. Indices fetched as
// wave-uniform scalar loads (kg = t>>7 is uniform per wave). LDS pitch 72 B
// (18 words, 16 distinct banks, <=2-way conflicts = free). Prep fused into
// one kernel (transpose + mask compaction).

#define B_    256
#define IN_   1024
#define OUT_  512
#define DS_   128
#define PITCH 72            // bytes per LDS row: 32 bf16 (64 B) + 8 pad
#define CHB   (128 * PITCH) // bytes per 128-row k-chunk tile

typedef float  f32x4  __attribute__((ext_vector_type(4)));
typedef short  short8 __attribute__((ext_vector_type(8)));

static __device__ __forceinline__ unsigned short f2bf(float f) {
    unsigned u = __builtin_bit_cast(unsigned, f);
    u = u + 0x7fff + ((u >> 16) & 1);          // RNE
    return (unsigned short)(u >> 16);
}

// ws layout:
//   [0, 512 KiB)            xTbf ushort[IN_][B_]  (bf16)
//   [1 MiB, +2 KiB)         cnt  int[OUT_]
//   [1 MiB + 4 KiB, +2 MiB) idx  int[OUT_][IN_]

__global__ __launch_bounds__(256) void prep_kernel(const float* __restrict__ x,
                                                   unsigned short* __restrict__ xTbf,
                                                   const float* __restrict__ mask,
                                                   int* __restrict__ cnt,
                                                   int* __restrict__ idx) {
    __shared__ float tile[64][65];
    __shared__ int   wsum[4];
    int bid = blockIdx.x;
    int t   = threadIdx.x;

    if (bid < 64) {                            // ---- transpose x -> bf16 xT ----
        int c  = t & 63;
        int r0 = t >> 6;
        int i0 = (bid & 15) * 64;
        int b0 = (bid >> 4) * 64;
#pragma unroll
        for (int k = 0; k < 16; ++k) {
            int r = r0 + k * 4;
            tile[r][c] = x[(size_t)(b0 + r) * IN_ + i0 + c];
        }
        __syncthreads();
#pragma unroll
        for (int k = 0; k < 16; ++k) {
            int r = r0 + k * 4;
            xTbf[(size_t)(i0 + r) * B_ + b0 + c] = f2bf(tile[c][r]);
        }
    } else {                                   // ---- compact mask row o ----
        int o    = bid - 64;
        int lane = t & 63;
        int wv   = t >> 6;
        const float* mrow = mask + (size_t)o * IN_;

        int loc[4];
        int c = 0;
        int ibase = t * 4;
#pragma unroll
        for (int k = 0; k < 4; ++k) {
            if (mrow[ibase + k] != 0.0f) loc[c++] = ibase + k;
        }
        int v = c;
#pragma unroll
        for (int off = 1; off < 64; off <<= 1) {
            int u = __shfl_up(v, off, 64);
            if (lane >= off) v += u;
        }
        if (lane == 63) wsum[wv] = v;
        __syncthreads();
        int base = 0;
        for (int w = 0; w < wv; ++w) base += wsum[w];
        int excl = base + v - c;

        int* orow = idx + (size_t)o * IN_;
        for (int k = 0; k < c; ++k) orow[excl + k] = loc[k];
        if (t == 255) cnt[o] = base + v;
    }
}

__global__ __launch_bounds__(512, 4) void spmm_mfma(const unsigned short* __restrict__ xTbf,
                                                    const float* __restrict__ peso,
                                                    const int* __restrict__ cnt,
                                                    const int* __restrict__ idx,
                                                    float* __restrict__ out) {
    __shared__ char xa[4 * CHB];               // xa[c][b=0..127][k bf16], pitch 72
    __shared__ char wt[4 * CHB];               // wT[c][ds=0..127][k bf16]

    int bid  = blockIdx.x;
    int c8   = bid & 7;                        // XCD id (round-robin dispatch)
    int m    = bid >> 3;
    int o    = (m >> 1) * 8 + c8;              // both halves of an o -> same XCD
    int half = m & 1;
    int t    = threadIdx.x;
    int lane = t & 63;
    int wv   = __builtin_amdgcn_readfirstlane(t >> 6);
    int wr   = wv & 3;                         // row group: 32 b-rows
    int wc   = wv >> 2;                        // col group: 64 ds-cols

    int n = cnt[o];
    const int* irow = idx + (size_t)o * IN_;

    int sds = t & 127;                         // staging row (b or ds)
    int kg  = t >> 7;                          // k-octet 0..3 (uniform per wave)
    const unsigned short* xrow = xTbf + half * 128 + sds;
    const float*          wrow = peso + (size_t)o * IN_ * DS_ + sds;
    int st_off = sds * PITCH + kg * 16;
    int a_off  = (wr * 32 + (lane & 15)) * PITCH + (lane >> 4) * 16;
    int b_off  = (wc * 64 + (lane & 15)) * PITCH + (lane >> 4) * 16;

    f32x4 acc[2][4];
#pragma unroll
    for (int a = 0; a < 2; ++a)
#pragma unroll
        for (int b = 0; b < 4; ++b) acc[a][b] = (f32x4){0.f, 0.f, 0.f, 0.f};

    for (int k0 = 0; k0 < n; k0 += 128) {
        if (k0) __syncthreads();               // protect LDS from prev readers
#pragma unroll
        for (int c = 0; c < 4; ++c) {          // stage chunk c (32 k-rows)
            int kb = k0 + c * 32 + (kg << 3);
            unsigned short xv[8];
            float          wf[8];
#pragma unroll
            for (int j = 0; j < 8; ++j) {
                int kk  = kb + j;              // wave-uniform
                int ok  = kk < n;
                int kks = ok ? kk : 0;
                int i   = irow[kks];           // uniform -> scalar load
                unsigned short xu = xrow[(size_t)i * B_];
                float          wl = wrow[(size_t)i * DS_];
                xv[j] = ok ? xu : (unsigned short)0;
                wf[j] = ok ? wl : 0.0f;
            }
            uint4 xw, ww;
            xw.x = (unsigned)xv[0] | ((unsigned)xv[1] << 16);
            xw.y = (unsigned)xv[2] | ((unsigned)xv[3] << 16);
            xw.z = (unsigned)xv[4] | ((unsigned)xv[5] << 16);
            xw.w = (unsigned)xv[6] | ((unsigned)xv[7] << 16);
            ww.x = (unsigned)f2bf(wf[0]) | ((unsigned)f2bf(wf[1]) << 16);
            ww.y = (unsigned)f2bf(wf[2]) | ((unsigned)f2bf(wf[3]) << 16);
            ww.z = (unsigned)f2bf(wf[4]) | ((unsigned)f2bf(wf[5]) << 16);
            ww.w = (unsigned)f2bf(wf[6]) | ((unsigned)f2bf(wf[7]) << 16);
            *(uint4*)(xa + c * CHB + st_off) = xw;
            *(uint4*)(wt + c * CHB + st_off) = ww;
        }
        __syncthreads();                       // tiles ready

#pragma unroll
        for (int c = 0; c < 4; ++c) {
            short8 afr[2], bfr[4];
#pragma unroll
            for (int rt = 0; rt < 2; ++rt)
                afr[rt] = *(const short8*)(xa + c * CHB + a_off + rt * 16 * PITCH);
#pragma unroll
            for (int ct = 0; ct < 4; ++ct)
                bfr[ct] = *(const short8*)(wt + c * CHB + b_off + ct * 16 * PITCH);
#pragma unroll
            for (int rt = 0; rt < 2; ++rt)
#pragma unroll
                for (int ct = 0; ct < 4; ++ct)
                    acc[rt][ct] = __builtin_amdgcn_mfma_f32_16x16x32_bf16(
                        afr[rt], bfr[ct], acc[rt][ct], 0, 0, 0);
        }
    }

    // C/D layout (m89): col = lane&15, row = (lane>>4)*4 + q
    float* obase = out + (size_t)(half * 128 + wr * 32 + (lane >> 4) * 4) * (OUT_ * DS_)
                 + o * DS_ + wc * 64 + (lane & 15);
#pragma unroll
    for (int rt = 0; rt < 2; ++rt)
#pragma unroll
        for (int ct = 0; ct < 4; ++ct)
#pragma unroll
            for (int q = 0; q < 4; ++q)
                obase[(size_t)(rt * 16 + q) * (OUT_ * DS_) + ct * 16] = acc[rt][ct][q];
}

extern "C" void kernel_launch(void* const* d_in, const int* in_sizes, int n_in,
                              void* d_out, int out_size, void* d_ws, size_t ws_size,
                              hipStream_t stream) {
    const float* x    = (const float*)d_in[0];
    const float* peso = (const float*)d_in[1];
    const float* mask = (const float*)d_in[2];
    float* out = (float*)d_out;

    char* ws = (char*)d_ws;
    unsigned short* xTbf = (unsigned short*)ws;
    int*            cnt  = (int*)(ws + (1 << 20));
    int*            idx  = (int*)(ws + (1 << 20) + 4096);

    prep_kernel<<<64 + OUT_, 256, 0, stream>>>(x, xTbf, mask, cnt, idx);
    spmm_mfma<<<OUT_ * 2, 512, 0, stream>>>(xTbf, peso, cnt, idx, out);
}